// Round 1
// baseline (779.263 us; speedup 1.0000x reference)
//
#include <hip/hip_runtime.h>
#include <cstdint>
#include <cstddef>

// GAT layer, bs=4, N=4096, Fin=Fout=256.
// Pipeline:
//  K1: h = X@W (fp32, LDS-tiled), plus f1' = (h@a1)*log2e, f2' = (h@a2)*log2e
//  K2: per-COLUMN (axis=1) online softmax stats over i, split by rows into 32
//      partials; also emits adj bitmask (1 bit/entry) via __ballot
//  K3: combine partials -> M'[b,j], S[b,j]
//  K4: hst[b][f][j] = bf16(h[b][j][f] / S[b,j])   (transposed, /S folded)
//  K5: h'[i,f] = sum_j exp2(leaky(f1'+f2') - M'_j) * hst[f][j] via bf16 MFMA,
//      A-fragments generated on the fly from f1',f2',M',mask; ELU epilogue.
// ws layout (needs ~38 MB):
//  h fp32 16MB | hst bf16 8MB | mask u64 8MB | f1p/f2p/Mfin/Sfin 64KB each | Mp/Sp 2MB each

#define GAT_ALPHA 0.2f
#define NEG_BIG_F -9000000000000000.0f
#define LOG2E 1.4426950408889634f

#if __has_builtin(__builtin_amdgcn_exp2f)
__device__ __forceinline__ float exp2_fast(float x){ return __builtin_amdgcn_exp2f(x); }
#else
__device__ __forceinline__ float exp2_fast(float x){ return exp2f(x); }
#endif

typedef __bf16 bf16x8 __attribute__((ext_vector_type(8)));
typedef __bf16 bf16x4 __attribute__((ext_vector_type(4)));
typedef float  f32x4  __attribute__((ext_vector_type(4)));

// ---------------- K1: h = X @ W, f1/f2 dots (fp32) ----------------
// grid (64 i-tiles, 4 batches), block 256. Tile: 64 rows x 256 cols, K-tiles of 64.
__global__ __launch_bounds__(256) void k1_h_gemm(
    const float* __restrict__ inp, const float* __restrict__ W,
    const float* __restrict__ avec, float* __restrict__ h,
    float* __restrict__ f1p, float* __restrict__ f2p)
{
  const int b  = blockIdx.y;
  const int i0 = blockIdx.x * 64;
  const int tid = threadIdx.x;
  const int tr = tid >> 5;   // 0..7 (row group of 8)
  const int tc = tid & 31;   // 0..31 (col group of 8)
  __shared__ float Wt[64][256];
  __shared__ float in_t[64][64];
  float acc[8][8];
  #pragma unroll
  for (int r = 0; r < 8; ++r)
    #pragma unroll
    for (int c = 0; c < 8; ++c) acc[r][c] = 0.f;

  const float* inb = inp + (size_t)b * 4096 * 256;
  for (int kt = 0; kt < 4; ++kt) {
    #pragma unroll
    for (int e = 0; e < 16; ++e) {            // stage W[kt*64 .. +64][0..256)
      int flat4 = e * 256 + tid;              // 4096 float4s
      int kk = flat4 >> 6;
      int ff = (flat4 & 63) * 4;
      *(float4*)&Wt[kk][ff] = *(const float4*)(W + (size_t)(kt*64 + kk) * 256 + ff);
    }
    #pragma unroll
    for (int e = 0; e < 4; ++e) {             // stage X tile [64 rows][64 k]
      int flat4 = e * 256 + tid;              // 1024 float4s
      int row = flat4 >> 4;
      int col = (flat4 & 15) * 4;
      *(float4*)&in_t[row][col] = *(const float4*)(inb + (size_t)(i0 + row) * 256 + kt*64 + col);
    }
    __syncthreads();
    for (int k = 0; k < 64; ++k) {
      float av[8], bv[8];
      #pragma unroll
      for (int r = 0; r < 8; ++r) av[r] = in_t[tr*8 + r][k];   // broadcast reads
      float4 b0 = *(float4*)&Wt[k][tc*8];
      float4 b1 = *(float4*)&Wt[k][tc*8 + 4];
      bv[0]=b0.x; bv[1]=b0.y; bv[2]=b0.z; bv[3]=b0.w;
      bv[4]=b1.x; bv[5]=b1.y; bv[6]=b1.z; bv[7]=b1.w;
      #pragma unroll
      for (int r = 0; r < 8; ++r)
        #pragma unroll
        for (int c = 0; c < 8; ++c)
          acc[r][c] = fmaf(av[r], bv[c], acc[r][c]);
    }
    __syncthreads();
  }

  float* hb = h + (size_t)b * 4096 * 256;
  #pragma unroll
  for (int r = 0; r < 8; ++r) {
    int i = i0 + tr*8 + r;
    float4 o0 = make_float4(acc[r][0], acc[r][1], acc[r][2], acc[r][3]);
    float4 o1 = make_float4(acc[r][4], acc[r][5], acc[r][6], acc[r][7]);
    *(float4*)(hb + (size_t)i * 256 + tc*8)     = o0;
    *(float4*)(hb + (size_t)i * 256 + tc*8 + 4) = o1;
  }

  // f1 = h.a1, f2 = h.a2 (fp32, pre-rounding accumulators), scaled by log2e
  float a1r[8], a2r[8];
  {
    float4 x0 = *(const float4*)(avec + tc*8);
    float4 x1 = *(const float4*)(avec + tc*8 + 4);
    a1r[0]=x0.x; a1r[1]=x0.y; a1r[2]=x0.z; a1r[3]=x0.w;
    a1r[4]=x1.x; a1r[5]=x1.y; a1r[6]=x1.z; a1r[7]=x1.w;
    float4 y0 = *(const float4*)(avec + 256 + tc*8);
    float4 y1 = *(const float4*)(avec + 256 + tc*8 + 4);
    a2r[0]=y0.x; a2r[1]=y0.y; a2r[2]=y0.z; a2r[3]=y0.w;
    a2r[4]=y1.x; a2r[5]=y1.y; a2r[6]=y1.z; a2r[7]=y1.w;
  }
  #pragma unroll
  for (int r = 0; r < 8; ++r) {
    float v1 = 0.f, v2 = 0.f;
    #pragma unroll
    for (int c = 0; c < 8; ++c) { v1 = fmaf(acc[r][c], a1r[c], v1); v2 = fmaf(acc[r][c], a2r[c], v2); }
    #pragma unroll
    for (int off = 16; off >= 1; off >>= 1) {
      v1 += __shfl_xor(v1, off);
      v2 += __shfl_xor(v2, off);
    }
    if (tc == 0) {
      int i = i0 + tr*8 + r;
      f1p[b*4096 + i] = v1 * LOG2E;
      f2p[b*4096 + i] = v2 * LOG2E;
    }
  }
}

// ---------------- K2: column-wise online softmax partials + bitmask ----------------
// grid (4 j-tiles, 32 row-splits, 4 batches), block 256; thread owns 4 columns (stride 256).
__global__ __launch_bounds__(256) void k2_colstats(
    const int* __restrict__ adj, const float* __restrict__ f1p, const float* __restrict__ f2p,
    float* __restrict__ Mp, float* __restrict__ Sp, unsigned long long* __restrict__ mask)
{
  const int jt = blockIdx.x, sp = blockIdx.y, b = blockIdx.z;
  const int tid = threadIdx.x;
  const int wv = tid >> 6, lane = tid & 63;
  const int j0 = jt * 1024;
  const int i0 = sp * 128;

  float f2v[4], m[4], s[4];
  #pragma unroll
  for (int g = 0; g < 4; ++g) {
    f2v[g] = f2p[b*4096 + j0 + g*256 + tid];
    m[g] = -INFINITY; s[g] = 0.f;
  }
  const int* adjb = adj + ((size_t)b * 4096 + i0) * 4096 + j0;

  #pragma unroll 2
  for (int ii = 0; ii < 128; ++ii) {
    const int i = i0 + ii;
    const float f1v = f1p[b*4096 + i];
    const int* arow = adjb + (size_t)ii * 4096;
    #pragma unroll
    for (int g = 0; g < 4; ++g) {
      int av = arow[g*256 + tid];
      float t = f1v + f2v[g];
      float e = fmaxf(t, GAT_ALPHA * t);
      bool pr = av > 0;
      float l = pr ? e : NEG_BIG_F;
      float nm = fmaxf(m[g], l);
      s[g] = s[g] * exp2_fast(m[g] - nm) + exp2_fast(l - nm);
      m[g] = nm;
      unsigned long long bal = __ballot(pr);
      if (lane == 0)
        mask[(size_t)(b*4096 + i) * 64 + ((j0 + g*256 + wv*64) >> 6)] = bal;
    }
  }
  #pragma unroll
  for (int g = 0; g < 4; ++g) {
    int c = b*4096 + j0 + g*256 + tid;      // flattened (b,j)
    Mp[sp * 16384 + c] = m[g];
    Sp[sp * 16384 + c] = s[g];
  }
}

// ---------------- K3: combine 32 partials ----------------
__global__ __launch_bounds__(256) void k3_combine(
    const float* __restrict__ Mp, const float* __restrict__ Sp,
    float* __restrict__ Mfin, float* __restrict__ Sfin)
{
  const int c = blockIdx.x * 256 + threadIdx.x;
  float m = -INFINITY;
  #pragma unroll
  for (int sp = 0; sp < 32; ++sp) m = fmaxf(m, Mp[sp * 16384 + c]);
  float s = 0.f;
  #pragma unroll
  for (int sp = 0; sp < 32; ++sp) s += Sp[sp * 16384 + c] * exp2_fast(Mp[sp * 16384 + c] - m);
  Mfin[c] = m; Sfin[c] = s;
}

// ---------------- K4: hst[b][f][j] = bf16(h[b][j][f] / S) ----------------
// grid (64 j-tiles, 4 f-tiles, 4 batches), block 256, 64x64 transpose tiles.
__global__ __launch_bounds__(256) void k4_scale_T(
    const float* __restrict__ h, const float* __restrict__ Sfin, __bf16* __restrict__ hst)
{
  const int b = blockIdx.z, f0 = blockIdx.y * 64, j0 = blockIdx.x * 64;
  const int tid = threadIdx.x;
  __shared__ float tile[64][65];
  __shared__ float sinv[64];
  if (tid < 64) sinv[tid] = 1.f / Sfin[b*4096 + j0 + tid];
  const float* hb = h + (size_t)b * 4096 * 256;
  #pragma unroll
  for (int e = 0; e < 4; ++e) {
    int flat4 = e * 256 + tid;
    int jj = flat4 >> 4;
    int ff = (flat4 & 15) * 4;
    float4 v = *(const float4*)(hb + (size_t)(j0 + jj) * 256 + f0 + ff);
    tile[jj][ff] = v.x; tile[jj][ff+1] = v.y; tile[jj][ff+2] = v.z; tile[jj][ff+3] = v.w;
  }
  __syncthreads();
  __bf16* hstb = hst + (size_t)b * 256 * 4096;
  #pragma unroll
  for (int e = 0; e < 4; ++e) {
    int flat4 = e * 256 + tid;
    int fr = flat4 >> 4;
    int jj = (flat4 & 15) * 4;
    bf16x4 o;
    #pragma unroll
    for (int q = 0; q < 4; ++q) o[q] = (__bf16)(tile[jj + q][fr] * sinv[jj + q]);
    *(bf16x4*)(hstb + (size_t)(f0 + fr) * 4096 + j0 + jj) = o;
  }
}

// ---------------- K5: h' = att @ h via bf16 MFMA + ELU ----------------
// grid (2 f-tiles, 64 i-tiles, 4 batches), block 256 = 4 waves in 2x2.
// Wave tile 32(i) x 64(f); block tile 64 x 128. K-chunks of 64 j, K-step 32.
// A/B k-convention (both sides): k = (lane>>4)*8 + r  -> HW permutation cancels.
// C/D: row=(lane>>4)*4+reg, col=lane&15  [HW-verified].
__global__ __launch_bounds__(256) void k5_attn_gemm(
    const __bf16* __restrict__ hst, const float* __restrict__ f1p, const float* __restrict__ f2p,
    const float* __restrict__ Mfin, const unsigned long long* __restrict__ mask,
    float* __restrict__ out)
{
  const int ft = blockIdx.x, it = blockIdx.y, b = blockIdx.z;
  const int tid = threadIdx.x;
  const int wid = tid >> 6, lane = tid & 63;
  const int wr = wid >> 1, wc = wid & 1;
  const int l15 = lane & 15, h4 = lane >> 4;
  const int i_w = it * 64 + wr * 32;
  const int f_blk = ft * 128;

  __shared__ __align__(16) char smemB[16384];   // [128 f][64 j] bf16, XOR-swizzled
  __shared__ float f2all[4096];
  __shared__ float Mall[4096];

  #pragma unroll
  for (int e = 0; e < 16; ++e) {
    int idx = e * 256 + tid;
    f2all[idx] = f2p[b*4096 + idx];
    Mall[idx]  = Mfin[b*4096 + idx];
  }
  float f1r[2];
  #pragma unroll
  for (int mf = 0; mf < 2; ++mf) f1r[mf] = f1p[b*4096 + i_w + mf*16 + l15];

  f32x4 acc[2][4];
  #pragma unroll
  for (int mf = 0; mf < 2; ++mf)
    #pragma unroll
    for (int nf = 0; nf < 4; ++nf)
      #pragma unroll
      for (int r = 0; r < 4; ++r) acc[mf][nf][r] = 0.f;

  const char* hstB = (const char*)(hst + (size_t)b * 256 * 4096);
  __syncthreads();

  for (int ch = 0; ch < 64; ++ch) {
    const int jc = ch * 64;
    // stage B tile: LDS linear dest, pre-swizzled global source
    #pragma unroll
    for (int e = 0; e < 4; ++e) {
      int c16 = e * 256 + tid;           // 1024 x 16B
      int f = c16 >> 3;                  // local f 0..127
      int w = (c16 & 7) << 4;            // byte in row
      int wsz = w ^ ((f & 7) << 4);
      uint4 v = *(const uint4*)(hstB + ((size_t)(f_blk + f) * 4096 + jc) * 2 + wsz);
      *(uint4*)(smemB + f * 128 + w) = v;
    }
    unsigned long long mw[2];
    #pragma unroll
    for (int mf = 0; mf < 2; ++mf)
      mw[mf] = mask[(size_t)(b*4096 + i_w + mf*16 + l15) * 64 + (jc >> 6)];
    __syncthreads();

    #pragma unroll
    for (int ks = 0; ks < 2; ++ks) {
      bf16x8 bfr[4];
      #pragma unroll
      for (int nf = 0; nf < 4; ++nf) {
        int f_local = wc * 64 + nf * 16 + l15;
        int byteoff = f_local * 128 + ((ks * 64 + h4 * 16) ^ ((f_local & 7) << 4));
        bfr[nf] = *(const bf16x8*)(smemB + byteoff);
      }
      const int jb = jc + ks * 32 + h4 * 8;
      float4 F0 = *(const float4*)&f2all[jb];
      float4 F1 = *(const float4*)&f2all[jb + 4];
      float4 M0 = *(const float4*)&Mall[jb];
      float4 M1 = *(const float4*)&Mall[jb + 4];
      float f2vv[8] = {F0.x,F0.y,F0.z,F0.w,F1.x,F1.y,F1.z,F1.w};
      float Mvv[8]  = {M0.x,M0.y,M0.z,M0.w,M1.x,M1.y,M1.z,M1.w};
      #pragma unroll
      for (int mf = 0; mf < 2; ++mf) {
        unsigned int bits = (unsigned int)(mw[mf] >> (ks * 32 + h4 * 8)) & 0xFFu;
        float f1v = f1r[mf];
        bf16x8 af;
        #pragma unroll
        for (int r = 0; r < 8; ++r) {
          float t = f1v + f2vv[r];
          float e = fmaxf(t, GAT_ALPHA * t);
          float p = exp2_fast(e - Mvv[r]);
          p = ((bits >> r) & 1u) ? p : 0.f;
          af[r] = (__bf16)p;
        }
        #pragma unroll
        for (int nf = 0; nf < 4; ++nf)
          acc[mf][nf] = __builtin_amdgcn_mfma_f32_16x16x32_bf16(af, bfr[nf], acc[mf][nf], 0, 0, 0);
      }
    }
    __syncthreads();
  }

  float* outb = out + (size_t)b * 4096 * 256;
  #pragma unroll
  for (int mf = 0; mf < 2; ++mf)
    #pragma unroll
    for (int nf = 0; nf < 4; ++nf)
      #pragma unroll
      for (int r = 0; r < 4; ++r) {
        float x = acc[mf][nf][r];
        float o = x > 0.f ? x : __expf(x) - 1.f;   // ELU
        int i = i_w + mf * 16 + h4 * 4 + r;
        int f = f_blk + wc * 64 + nf * 16 + l15;
        outb[(size_t)i * 256 + f] = o;
      }
}

extern "C" void kernel_launch(void* const* d_in, const int* in_sizes, int n_in,
                              void* d_out, int out_size, void* d_ws, size_t ws_size,
                              hipStream_t stream) {
  const float* inp  = (const float*)d_in[0];
  const int*   adj  = (const int*)d_in[1];
  const float* W    = (const float*)d_in[2];
  const float* avec = (const float*)d_in[3];
  float* out = (float*)d_out;
  char* ws = (char*)d_ws;

  float* h    = (float*)(ws);                               // 16 MB
  __bf16* hst = (__bf16*)(ws + 16777216);                   // 8 MB
  unsigned long long* mask = (unsigned long long*)(ws + 25165824); // 8 MB
  float* f1p  = (float*)(ws + 33554432);
  float* f2p  = (float*)(ws + 33619968);
  float* Mfin = (float*)(ws + 33685504);
  float* Sfin = (float*)(ws + 33751040);
  float* Mp   = (float*)(ws + 33816576);                    // 2 MB
  float* Sp   = (float*)(ws + 35913728);                    // 2 MB

  k1_h_gemm<<<dim3(64, 4), 256, 0, stream>>>(inp, W, avec, h, f1p, f2p);
  k2_colstats<<<dim3(4, 32, 4), 256, 0, stream>>>(adj, f1p, f2p, Mp, Sp, mask);
  k3_combine<<<64, 256, 0, stream>>>(Mp, Sp, Mfin, Sfin);
  k4_scale_T<<<dim3(64, 4, 4), 256, 0, stream>>>(h, Sfin, hst);
  k5_attn_gemm<<<dim3(2, 64, 4), 256, 0, stream>>>(hst, f1p, f2p, Mfin, mask, out);
}

// Round 4
// 644.764 us; speedup vs baseline: 1.2086x; 1.2086x over previous
//
#include <hip/hip_runtime.h>
#include <cstdint>
#include <cstddef>

// GAT layer, bs=4, N=4096, Fin=Fout=256.
// Pipeline (no-max softmax: t bounded by ~±30 log2-units, exp2/S fit fp32 easily,
// and S_j >= exp2(t_ij) guarantees every MFMA product is bounded by |h|):
//  K1: h = X@W (fp32), f1' = (h@a1)*log2e, f2' = (h@a2)*log2e
//  K2: stream adj (256MB): emit bitmask (row-major, for K5) + per-column
//      partial sums S over 64 i-chunks.  exp2 is OFF the dependency chain.
//  K3: combine 64 partials -> Sfin[b,j]
//  K4: hst[b][f][j] = bf16(h[b][j][f] / S[b,j])   (transposed, /S folded)
//  K5: h'[i,f] = sum_j exp2(leaky(f1'+f2')) * hst[f][j] via bf16 MFMA,
//      A-fragments generated on the fly; ELU epilogue.
// ws: h 16MB | hst 8MB | mask 8MB | f1p/f2p/Sfin 64KB | Sp 4MB  (~36.3MB)

#define GAT_ALPHA 0.2f
#define LOG2E 1.4426950408889634f

#if __has_builtin(__builtin_amdgcn_exp2f)
__device__ __forceinline__ float exp2_fast(float x){ return __builtin_amdgcn_exp2f(x); }
#else
__device__ __forceinline__ float exp2_fast(float x){ return exp2f(x); }
#endif

typedef __bf16 bf16x8 __attribute__((ext_vector_type(8)));
typedef __bf16 bf16x4 __attribute__((ext_vector_type(4)));
typedef float  f32x4  __attribute__((ext_vector_type(4)));

// ---------------- K1: h = X @ W, f1/f2 dots (fp32) ----------------
__global__ __launch_bounds__(256) void k1_h_gemm(
    const float* __restrict__ inp, const float* __restrict__ W,
    const float* __restrict__ avec, float* __restrict__ h,
    float* __restrict__ f1p, float* __restrict__ f2p)
{
  const int b  = blockIdx.y;
  const int i0 = blockIdx.x * 64;
  const int tid = threadIdx.x;
  const int tr = tid >> 5;   // 0..7 (row group of 8)
  const int tc = tid & 31;   // 0..31 (col group of 8)
  __shared__ float Wt[64][256];
  __shared__ float in_t[64][64];
  float acc[8][8];
  #pragma unroll
  for (int r = 0; r < 8; ++r)
    #pragma unroll
    for (int c = 0; c < 8; ++c) acc[r][c] = 0.f;

  const float* inb = inp + (size_t)b * 4096 * 256;
  for (int kt = 0; kt < 4; ++kt) {
    #pragma unroll
    for (int e = 0; e < 16; ++e) {
      int flat4 = e * 256 + tid;
      int kk = flat4 >> 6;
      int ff = (flat4 & 63) * 4;
      *(float4*)&Wt[kk][ff] = *(const float4*)(W + (size_t)(kt*64 + kk) * 256 + ff);
    }
    #pragma unroll
    for (int e = 0; e < 4; ++e) {
      int flat4 = e * 256 + tid;
      int row = flat4 >> 4;
      int col = (flat4 & 15) * 4;
      *(float4*)&in_t[row][col] = *(const float4*)(inb + (size_t)(i0 + row) * 256 + kt*64 + col);
    }
    __syncthreads();
    for (int k = 0; k < 64; ++k) {
      float av[8], bv[8];
      #pragma unroll
      for (int r = 0; r < 8; ++r) av[r] = in_t[tr*8 + r][k];
      float4 b0 = *(float4*)&Wt[k][tc*8];
      float4 b1 = *(float4*)&Wt[k][tc*8 + 4];
      bv[0]=b0.x; bv[1]=b0.y; bv[2]=b0.z; bv[3]=b0.w;
      bv[4]=b1.x; bv[5]=b1.y; bv[6]=b1.z; bv[7]=b1.w;
      #pragma unroll
      for (int r = 0; r < 8; ++r)
        #pragma unroll
        for (int c = 0; c < 8; ++c)
          acc[r][c] = fmaf(av[r], bv[c], acc[r][c]);
    }
    __syncthreads();
  }

  float* hb = h + (size_t)b * 4096 * 256;
  #pragma unroll
  for (int r = 0; r < 8; ++r) {
    int i = i0 + tr*8 + r;
    float4 o0 = make_float4(acc[r][0], acc[r][1], acc[r][2], acc[r][3]);
    float4 o1 = make_float4(acc[r][4], acc[r][5], acc[r][6], acc[r][7]);
    *(float4*)(hb + (size_t)i * 256 + tc*8)     = o0;
    *(float4*)(hb + (size_t)i * 256 + tc*8 + 4) = o1;
  }

  float a1r[8], a2r[8];
  {
    float4 x0 = *(const float4*)(avec + tc*8);
    float4 x1 = *(const float4*)(avec + tc*8 + 4);
    a1r[0]=x0.x; a1r[1]=x0.y; a1r[2]=x0.z; a1r[3]=x0.w;
    a1r[4]=x1.x; a1r[5]=x1.y; a1r[6]=x1.z; a1r[7]=x1.w;
    float4 y0 = *(const float4*)(avec + 256 + tc*8);
    float4 y1 = *(const float4*)(avec + 256 + tc*8 + 4);
    a2r[0]=y0.x; a2r[1]=y0.y; a2r[2]=y0.z; a2r[3]=y0.w;
    a2r[4]=y1.x; a2r[5]=y1.y; a2r[6]=y1.z; a2r[7]=y1.w;
  }
  #pragma unroll
  for (int r = 0; r < 8; ++r) {
    float v1 = 0.f, v2 = 0.f;
    #pragma unroll
    for (int c = 0; c < 8; ++c) { v1 = fmaf(acc[r][c], a1r[c], v1); v2 = fmaf(acc[r][c], a2r[c], v2); }
    #pragma unroll
    for (int off = 16; off >= 1; off >>= 1) {
      v1 += __shfl_xor(v1, off);
      v2 += __shfl_xor(v2, off);
    }
    if (tc == 0) {
      int i = i0 + tr*8 + r;
      f1p[b*4096 + i] = v1 * LOG2E;
      f2p[b*4096 + i] = v2 * LOG2E;
    }
  }
}

// ---------------- K2: stream adj -> mask + partial column sums ----------------
// grid (4 j-tiles, 64 i-chunks, 4 batches) = 1024 blocks; block 256.
// Thread owns 4 columns (stride 256). exp2 independent per element; only the
// fadd accumulate chains (4 independent accumulators).
__global__ __launch_bounds__(256) void k2_stream(
    const int* __restrict__ adj, const float* __restrict__ f1p, const float* __restrict__ f2p,
    float* __restrict__ Sp, unsigned long long* __restrict__ mask)
{
  const int jt = blockIdx.x, sp = blockIdx.y, b = blockIdx.z;
  const int tid = threadIdx.x;
  const int wv = tid >> 6, lane = tid & 63;
  const int j0 = jt * 1024;
  const int i0 = sp * 64;

  __shared__ float f1s[64];
  if (tid < 64) f1s[tid] = f1p[b*4096 + i0 + tid];
  float f2v[4], s[4];
  #pragma unroll
  for (int g = 0; g < 4; ++g) {
    f2v[g] = f2p[b*4096 + j0 + g*256 + tid];
    s[g] = 0.f;
  }
  __syncthreads();

  const int* adjb = adj + ((size_t)b * 4096 + i0) * 4096 + j0;
  #pragma unroll 4
  for (int ii = 0; ii < 64; ++ii) {
    const float f1v = f1s[ii];
    const int* arow = adjb + (size_t)ii * 4096;
    #pragma unroll
    for (int g = 0; g < 4; ++g) {
      int av = arow[g*256 + tid];
      bool pr = av > 0;
      unsigned long long bal = __ballot(pr);
      if (lane == 0)
        mask[(size_t)(b*4096 + i0 + ii) * 64 + ((j0 + g*256 + wv*64) >> 6)] = bal;
      float t = f1v + f2v[g];
      float e = fmaxf(t, GAT_ALPHA * t);
      float p = exp2_fast(e);
      s[g] += pr ? p : 0.f;
    }
  }
  #pragma unroll
  for (int g = 0; g < 4; ++g)
    Sp[(size_t)sp * 16384 + b*4096 + j0 + g*256 + tid] = s[g];
}

// ---------------- K3: combine 64 partial sums ----------------
__global__ __launch_bounds__(256) void k3_combine(
    const float* __restrict__ Sp, float* __restrict__ Sfin)
{
  const int c = blockIdx.x * 256 + threadIdx.x;
  float s = 0.f;
  #pragma unroll
  for (int sp = 0; sp < 64; ++sp) s += Sp[(size_t)sp * 16384 + c];
  Sfin[c] = s;
}

// ---------------- K4: hst[b][f][j] = bf16(h[b][j][f] / S) ----------------
__global__ __launch_bounds__(256) void k4_scale_T(
    const float* __restrict__ h, const float* __restrict__ Sfin, __bf16* __restrict__ hst)
{
  const int b = blockIdx.z, f0 = blockIdx.y * 64, j0 = blockIdx.x * 64;
  const int tid = threadIdx.x;
  __shared__ float tile[64][65];
  __shared__ float sinv[64];
  if (tid < 64) {
    float S = Sfin[b*4096 + j0 + tid];
    sinv[tid] = S > 0.f ? 1.f / S : 0.f;
  }
  const float* hb = h + (size_t)b * 4096 * 256;
  #pragma unroll
  for (int e = 0; e < 4; ++e) {
    int flat4 = e * 256 + tid;
    int jj = flat4 >> 4;
    int ff = (flat4 & 15) * 4;
    float4 v = *(const float4*)(hb + (size_t)(j0 + jj) * 256 + f0 + ff);
    tile[jj][ff] = v.x; tile[jj][ff+1] = v.y; tile[jj][ff+2] = v.z; tile[jj][ff+3] = v.w;
  }
  __syncthreads();
  __bf16* hstb = hst + (size_t)b * 256 * 4096;
  #pragma unroll
  for (int e = 0; e < 4; ++e) {
    int flat4 = e * 256 + tid;
    int fr = flat4 >> 4;
    int jj = (flat4 & 15) * 4;
    bf16x4 o;
    #pragma unroll
    for (int q = 0; q < 4; ++q) o[q] = (__bf16)(tile[jj + q][fr] * sinv[jj + q]);
    *(bf16x4*)(hstb + (size_t)(f0 + fr) * 4096 + j0 + jj) = o;
  }
}

// ---------------- K5: h' = att @ h via bf16 MFMA + ELU (no max-sub) ----------------
// grid (2 f-tiles, 64 i-tiles, 4 batches), block 256 = 4 waves in 2x2.
// A/B k-convention (both sides): k = (lane>>4)*8 + r  -> HW permutation cancels.
// C/D: row=(lane>>4)*4+reg, col=lane&15.
__global__ __launch_bounds__(256) void k5_attn_gemm(
    const __bf16* __restrict__ hst, const float* __restrict__ f1p, const float* __restrict__ f2p,
    const unsigned long long* __restrict__ mask, float* __restrict__ out)
{
  const int ft = blockIdx.x, it = blockIdx.y, b = blockIdx.z;
  const int tid = threadIdx.x;
  const int wid = tid >> 6, lane = tid & 63;
  const int wr = wid >> 1, wc = wid & 1;
  const int l15 = lane & 15, h4 = lane >> 4;
  const int i_w = it * 64 + wr * 32;
  const int f_blk = ft * 128;

  __shared__ __align__(16) char smemB[16384];   // [128 f][64 j] bf16, XOR-swizzled
  __shared__ float f2all[4096];

  #pragma unroll
  for (int e = 0; e < 16; ++e) {
    int idx = e * 256 + tid;
    f2all[idx] = f2p[b*4096 + idx];
  }
  float f1r[2];
  #pragma unroll
  for (int mf = 0; mf < 2; ++mf) f1r[mf] = f1p[b*4096 + i_w + mf*16 + l15];

  f32x4 acc[2][4];
  #pragma unroll
  for (int mf = 0; mf < 2; ++mf)
    #pragma unroll
    for (int nf = 0; nf < 4; ++nf)
      #pragma unroll
      for (int r = 0; r < 4; ++r) acc[mf][nf][r] = 0.f;

  const char* hstB = (const char*)(hst + (size_t)b * 256 * 4096);
  __syncthreads();

  for (int ch = 0; ch < 64; ++ch) {
    const int jc = ch * 64;
    #pragma unroll
    for (int e = 0; e < 4; ++e) {
      int c16 = e * 256 + tid;
      int f = c16 >> 3;
      int w = (c16 & 7) << 4;
      int wsz = w ^ ((f & 7) << 4);
      uint4 v = *(const uint4*)(hstB + ((size_t)(f_blk + f) * 4096 + jc) * 2 + wsz);
      *(uint4*)(smemB + f * 128 + w) = v;
    }
    unsigned long long mw[2];
    #pragma unroll
    for (int mf = 0; mf < 2; ++mf)
      mw[mf] = mask[(size_t)(b*4096 + i_w + mf*16 + l15) * 64 + (jc >> 6)];
    __syncthreads();

    #pragma unroll
    for (int ks = 0; ks < 2; ++ks) {
      bf16x8 bfr[4];
      #pragma unroll
      for (int nf = 0; nf < 4; ++nf) {
        int f_local = wc * 64 + nf * 16 + l15;
        int byteoff = f_local * 128 + ((ks * 64 + h4 * 16) ^ ((f_local & 7) << 4));
        bfr[nf] = *(const bf16x8*)(smemB + byteoff);
      }
      const int jb = jc + ks * 32 + h4 * 8;
      float4 F0 = *(const float4*)&f2all[jb];
      float4 F1 = *(const float4*)&f2all[jb + 4];
      float f2vv[8] = {F0.x,F0.y,F0.z,F0.w,F1.x,F1.y,F1.z,F1.w};
      #pragma unroll
      for (int mf = 0; mf < 2; ++mf) {
        unsigned int bits = (unsigned int)(mw[mf] >> (ks * 32 + h4 * 8)) & 0xFFu;
        float f1v = f1r[mf];
        bf16x8 af;
        #pragma unroll
        for (int r = 0; r < 8; ++r) {
          float t = f1v + f2vv[r];
          float e = fmaxf(t, GAT_ALPHA * t);
          float p = exp2_fast(e);
          af[r] = ((bits >> r) & 1u) ? (__bf16)p : (__bf16)0.f;
        }
        #pragma unroll
        for (int nf = 0; nf < 4; ++nf)
          acc[mf][nf] = __builtin_amdgcn_mfma_f32_16x16x32_bf16(af, bfr[nf], acc[mf][nf], 0, 0, 0);
      }
    }
    __syncthreads();
  }

  float* outb = out + (size_t)b * 4096 * 256;
  #pragma unroll
  for (int mf = 0; mf < 2; ++mf)
    #pragma unroll
    for (int nf = 0; nf < 4; ++nf)
      #pragma unroll
      for (int r = 0; r < 4; ++r) {
        float x = acc[mf][nf][r];
        float o = x > 0.f ? x : __expf(x) - 1.f;   // ELU
        int i = i_w + mf * 16 + h4 * 4 + r;
        int f = f_blk + wc * 64 + nf * 16 + l15;
        outb[(size_t)i * 256 + f] = o;
      }
}

extern "C" void kernel_launch(void* const* d_in, const int* in_sizes, int n_in,
                              void* d_out, int out_size, void* d_ws, size_t ws_size,
                              hipStream_t stream) {
  const float* inp  = (const float*)d_in[0];
  const int*   adj  = (const int*)d_in[1];
  const float* W    = (const float*)d_in[2];
  const float* avec = (const float*)d_in[3];
  float* out = (float*)d_out;
  char* ws = (char*)d_ws;

  float* h    = (float*)(ws);                               // 16 MB
  __bf16* hst = (__bf16*)(ws + 16777216);                   // 8 MB
  unsigned long long* mask = (unsigned long long*)(ws + 25165824); // 8 MB
  float* f1p  = (float*)(ws + 33554432);
  float* f2p  = (float*)(ws + 33619968);
  float* Sfin = (float*)(ws + 33685504);
  float* Sp   = (float*)(ws + 33751040);                    // 4 MB

  k1_h_gemm<<<dim3(64, 4), 256, 0, stream>>>(inp, W, avec, h, f1p, f2p);
  k2_stream<<<dim3(4, 64, 4), 256, 0, stream>>>(adj, f1p, f2p, Sp, mask);
  k3_combine<<<64, 256, 0, stream>>>(Sp, Sfin);
  k4_scale_T<<<dim3(64, 4, 4), 256, 0, stream>>>(h, Sfin, hst);
  k5_attn_gemm<<<dim3(2, 64, 4), 256, 0, stream>>>(hst, f1p, f2p, mask, out);
}

// Round 10
// 562.371 us; speedup vs baseline: 1.3857x; 1.1465x over previous
//
#include <hip/hip_runtime.h>
#include <cstdint>
#include <cstddef>

// GAT layer, bs=4, N=4096, Fin=Fout=256.
//  K0: Wt_bf[f][k] = bf16(W[k][f])  (transpose+convert, 128KB)
//  K1: h_bf = bf16(X@W) via 16x16x32 bf16 MFMA (LDS-staged, XOR-swizzled)
//  K15: f1' = (h@a1)*log2e, f2' = (h@a2)*log2e  (fp32 dots from h_bf)
//  K2: stream adj (256MB, int4 loads): 4-ballot bitmask + partial column sums
//  K3: combine 64 partials -> Sfin
//  K4: hst[b][f][j] = bf16(h_bf[b][j][f] / S[b,j])
//  K5: h'[i,f] = sum_j exp2(leaky(f1'+f2')) * hst[f][j] via MFMA; ELU.
// Mask layout: word idx ((b*4096+i)*16 + grp)*4 + p, bit l = adj(i, grp*256+l*4+p).
// ws: h_bf 8MB | hst 8MB | mask 8MB | Wt 128K | f1p/f2p/Sfin 64K | Sp 4MB (~28.4MB)
// R7 fix: k1 Ws staging indices were f=c16>>2/sg=c16&3 (512x4 chunks) -> OOB LDS
// writes + OOB Wt reads (into poisoned mask region) -> NaN. Correct: 256 rows x
// 8 chunks of 16B: f=c16>>3, sg=c16&7.

#define GAT_ALPHA 0.2f
#define LOG2E 1.4426950408889634f

#if __has_builtin(__builtin_amdgcn_exp2f)
__device__ __forceinline__ float exp2_fast(float x){ return __builtin_amdgcn_exp2f(x); }
#else
__device__ __forceinline__ float exp2_fast(float x){ return exp2f(x); }
#endif

typedef __bf16 bf16x8 __attribute__((ext_vector_type(8)));
typedef __bf16 bf16x4 __attribute__((ext_vector_type(4)));
typedef float  f32x4  __attribute__((ext_vector_type(4)));
typedef unsigned long long ull;

// ---------------- K0: Wt_bf[f][k] = bf16(W[k][f]) ----------------
__global__ __launch_bounds__(256) void k0_prep(
    const float* __restrict__ W, __bf16* __restrict__ Wt)
{
  const int f0 = blockIdx.x * 64, k0 = blockIdx.y * 64;
  const int tid = threadIdx.x;
  __shared__ float tile[64][65];
  #pragma unroll
  for (int e = 0; e < 4; ++e) {
    int flat4 = e * 256 + tid;
    int kk = flat4 >> 4;
    int ff = (flat4 & 15) * 4;
    float4 v = *(const float4*)(W + (size_t)(k0 + kk) * 256 + f0 + ff);
    tile[kk][ff] = v.x; tile[kk][ff+1] = v.y; tile[kk][ff+2] = v.z; tile[kk][ff+3] = v.w;
  }
  __syncthreads();
  #pragma unroll
  for (int e = 0; e < 4; ++e) {
    int flat4 = e * 256 + tid;
    int fr = flat4 >> 4;
    int kk = (flat4 & 15) * 4;
    bf16x4 o;
    #pragma unroll
    for (int q = 0; q < 4; ++q) o[q] = (__bf16)tile[kk + q][fr];
    *(bf16x4*)(Wt + (size_t)(f0 + fr) * 256 + k0 + kk) = o;
  }
}

// ---------------- K1: h_bf = X @ W via bf16 MFMA ----------------
// grid (64 i-tiles, 4 b), block 256 = 4 waves (2 row-halves x 2 col-halves).
// Wave tile 32i x 128f. K-tiles of 64, K-step 32. Same frag conventions as K5.
__global__ __launch_bounds__(256) void k1_mfma(
    const float* __restrict__ inp, const __bf16* __restrict__ Wt,
    __bf16* __restrict__ hbf)
{
  const int b = blockIdx.y, i0 = blockIdx.x * 64;
  const int tid = threadIdx.x;
  const int wid = tid >> 6, lane = tid & 63;
  const int wr = wid >> 1, wc = wid & 1;
  const int l15 = lane & 15, h4 = lane >> 4;

  __shared__ __align__(16) char Xs[8192];    // [64 i][64 k] bf16, XOR-swz by row
  __shared__ __align__(16) char Ws[32768];   // [256 f][64 k] bf16, XOR-swz by f

  f32x4 acc[2][8];
  #pragma unroll
  for (int mf = 0; mf < 2; ++mf)
    #pragma unroll
    for (int nf = 0; nf < 8; ++nf)
      #pragma unroll
      for (int q = 0; q < 4; ++q) acc[mf][nf][q] = 0.f;

  const float* inb = inp + (size_t)b * 4096 * 256;
  const char* WtB = (const char*)Wt;

  for (int kt = 0; kt < 4; ++kt) {
    { // stage Xs: thread -> row rX, 16 floats at kseg
      int rX = tid >> 2;
      int ks16 = (tid & 3) * 16;
      const float* src = inb + (size_t)(i0 + rX) * 256 + kt * 64 + ks16;
      float4 v0 = *(const float4*)(src);
      float4 v1 = *(const float4*)(src + 4);
      float4 v2 = *(const float4*)(src + 8);
      float4 v3 = *(const float4*)(src + 12);
      bf16x8 lo, hi;
      lo[0]=(__bf16)v0.x; lo[1]=(__bf16)v0.y; lo[2]=(__bf16)v0.z; lo[3]=(__bf16)v0.w;
      lo[4]=(__bf16)v1.x; lo[5]=(__bf16)v1.y; lo[6]=(__bf16)v1.z; lo[7]=(__bf16)v1.w;
      hi[0]=(__bf16)v2.x; hi[1]=(__bf16)v2.y; hi[2]=(__bf16)v2.z; hi[3]=(__bf16)v2.w;
      hi[4]=(__bf16)v3.x; hi[5]=(__bf16)v3.y; hi[6]=(__bf16)v3.z; hi[7]=(__bf16)v3.w;
      int swz = (rX & 7) << 4;
      *(bf16x8*)(Xs + rX * 128 + ((ks16 * 2) ^ swz))      = lo;
      *(bf16x8*)(Xs + rX * 128 + ((ks16 * 2 + 16) ^ swz)) = hi;
    }
    #pragma unroll
    for (int e = 0; e < 8; ++e) { // stage Ws: 2048 x 16B = [256 f][8 sg of 16B]
      int c16 = e * 256 + tid;
      int f = c16 >> 3;          // 0..255  (R7 fix: was >>2)
      int sg = c16 & 7;          // 0..7    (R7 fix: was &3)
      uint4 v = *(const uint4*)(WtB + (size_t)f * 512 + kt * 128 + sg * 16);
      *(uint4*)(Ws + f * 128 + ((sg * 16) ^ ((f & 7) << 4))) = v;
    }
    __syncthreads();
    #pragma unroll
    for (int ks = 0; ks < 2; ++ks) {
      bf16x8 afr[2];
      #pragma unroll
      for (int mf = 0; mf < 2; ++mf) {
        int row = wr * 32 + mf * 16 + l15;
        afr[mf] = *(const bf16x8*)(Xs + row * 128 + ((ks * 64 + h4 * 16) ^ ((row & 7) << 4)));
      }
      bf16x8 bfr[8];
      #pragma unroll
      for (int nf = 0; nf < 8; ++nf) {
        int f = wc * 128 + nf * 16 + l15;
        bfr[nf] = *(const bf16x8*)(Ws + f * 128 + ((ks * 64 + h4 * 16) ^ ((f & 7) << 4)));
      }
      #pragma unroll
      for (int mf = 0; mf < 2; ++mf)
        #pragma unroll
        for (int nf = 0; nf < 8; ++nf)
          acc[mf][nf] = __builtin_amdgcn_mfma_f32_16x16x32_bf16(afr[mf], bfr[nf], acc[mf][nf], 0, 0, 0);
    }
    __syncthreads();
  }

  __bf16* hb = hbf + ((size_t)b * 4096 + i0) * 256;
  #pragma unroll
  for (int mf = 0; mf < 2; ++mf)
    #pragma unroll
    for (int nf = 0; nf < 8; ++nf)
      #pragma unroll
      for (int q = 0; q < 4; ++q) {
        int i_loc = wr * 32 + mf * 16 + h4 * 4 + q;
        int f = wc * 128 + nf * 16 + l15;
        hb[(size_t)i_loc * 256 + f] = (__bf16)acc[mf][nf][q];
      }
}

// ---------------- K15: f1/f2 row dots from h_bf ----------------
// grid 4096 blocks, block 256 = 4 waves; one row per wave.
__global__ __launch_bounds__(256) void k15_f12(
    const __bf16* __restrict__ hbf, const float* __restrict__ avec,
    float* __restrict__ f1p, float* __restrict__ f2p)
{
  const int tid = threadIdx.x;
  const int row = blockIdx.x * 4 + (tid >> 6);
  const int lane = tid & 63;
  bf16x4 hv = *(const bf16x4*)(hbf + (size_t)row * 256 + lane * 4);
  float4 a1 = *(const float4*)(avec + lane * 4);
  float4 a2 = *(const float4*)(avec + 256 + lane * 4);
  float v1 = (float)hv[0]*a1.x + (float)hv[1]*a1.y + (float)hv[2]*a1.z + (float)hv[3]*a1.w;
  float v2 = (float)hv[0]*a2.x + (float)hv[1]*a2.y + (float)hv[2]*a2.z + (float)hv[3]*a2.w;
  #pragma unroll
  for (int off = 32; off >= 1; off >>= 1) {
    v1 += __shfl_xor(v1, off);
    v2 += __shfl_xor(v2, off);
  }
  if (lane == 0) {
    f1p[row] = v1 * LOG2E;
    f2p[row] = v2 * LOG2E;
  }
}

// ---------------- K2: stream adj (int4) -> 4-ballot mask + partial col sums ----------------
// grid (8 group-pairs, 64 row-chunks, 4 b) = 2048 blocks, block 128 = 2 waves.
// Wave wv owns 256-col group grp = jt8*2+wv; lane owns cols grp*256 + lane*4 .. +3.
__global__ __launch_bounds__(128) void k2_stream(
    const int* __restrict__ adj, const float* __restrict__ f1p, const float* __restrict__ f2p,
    float* __restrict__ Sp, ull* __restrict__ maskw)
{
  const int jt8 = blockIdx.x, sp = blockIdx.y, b = blockIdx.z;
  const int tid = threadIdx.x;
  const int wv = tid >> 6, lane = tid & 63;
  const int grp = jt8 * 2 + wv;
  const int i0 = sp * 64;

  __shared__ float f1s[64];
  if (tid < 64) f1s[tid] = f1p[b * 4096 + i0 + tid];

  float4 f2v = *(const float4*)(f2p + b * 4096 + grp * 256 + lane * 4);
  float s0 = 0.f, s1 = 0.f, s2 = 0.f, s3 = 0.f;
  __syncthreads();

  const int* adjb = adj + ((size_t)b * 4096 + i0) * 4096 + grp * 256 + lane * 4;
  #pragma unroll 8
  for (int ii = 0; ii < 64; ++ii) {
    int4 av = *(const int4*)(adjb + (size_t)ii * 4096);
    const float f1v = f1s[ii];
    bool p0 = av.x > 0, p1 = av.y > 0, p2 = av.z > 0, p3 = av.w > 0;
    ull b0 = __ballot(p0), b1 = __ballot(p1), b2 = __ballot(p2), b3 = __ballot(p3);
    if (lane == 0) {
      size_t wbase = ((size_t)(b * 4096 + i0 + ii) * 16 + grp) * 4;
      ulonglong2 m01; m01.x = b0; m01.y = b1;
      ulonglong2 m23; m23.x = b2; m23.y = b3;
      *(ulonglong2*)(maskw + wbase)     = m01;
      *(ulonglong2*)(maskw + wbase + 2) = m23;
    }
    float t0 = f1v + f2v.x, t1 = f1v + f2v.y, t2 = f1v + f2v.z, t3 = f1v + f2v.w;
    float e0 = fmaxf(t0, GAT_ALPHA * t0), e1 = fmaxf(t1, GAT_ALPHA * t1);
    float e2 = fmaxf(t2, GAT_ALPHA * t2), e3 = fmaxf(t3, GAT_ALPHA * t3);
    s0 += p0 ? exp2_fast(e0) : 0.f;
    s1 += p1 ? exp2_fast(e1) : 0.f;
    s2 += p2 ? exp2_fast(e2) : 0.f;
    s3 += p3 ? exp2_fast(e3) : 0.f;
  }
  float4 sv; sv.x = s0; sv.y = s1; sv.z = s2; sv.w = s3;
  *(float4*)(Sp + (size_t)sp * 16384 + b * 4096 + grp * 256 + lane * 4) = sv;
}

// ---------------- K3: combine 64 partial sums ----------------
__global__ __launch_bounds__(256) void k3_combine(
    const float* __restrict__ Sp, float* __restrict__ Sfin)
{
  const int c = blockIdx.x * 256 + threadIdx.x;
  float s = 0.f;
  #pragma unroll
  for (int sp = 0; sp < 64; ++sp) s += Sp[(size_t)sp * 16384 + c];
  Sfin[c] = s;
}

// ---------------- K4: hst[b][f][j] = bf16(h_bf[b][j][f] / S) ----------------
__global__ __launch_bounds__(256) void k4_scale_T(
    const __bf16* __restrict__ hbf, const float* __restrict__ Sfin, __bf16* __restrict__ hst)
{
  const int b = blockIdx.z, f0 = blockIdx.y * 64, j0 = blockIdx.x * 64;
  const int tid = threadIdx.x;
  __shared__ float tile[64][65];
  __shared__ float sinv[64];
  if (tid < 64) {
    float S = Sfin[b * 4096 + j0 + tid];
    sinv[tid] = S > 0.f ? 1.f / S : 0.f;
  }
  const __bf16* hb = hbf + (size_t)b * 4096 * 256;
  #pragma unroll
  for (int e = 0; e < 2; ++e) {
    int flat8 = e * 256 + tid;
    int jj = flat8 >> 3;
    int ff = (flat8 & 7) * 8;
    bf16x8 v = *(const bf16x8*)(hb + (size_t)(j0 + jj) * 256 + f0 + ff);
    #pragma unroll
    for (int q = 0; q < 8; ++q) tile[jj][ff + q] = (float)v[q];
  }
  __syncthreads();
  __bf16* hstb = hst + (size_t)b * 256 * 4096;
  #pragma unroll
  for (int e = 0; e < 4; ++e) {
    int flat4 = e * 256 + tid;
    int fr = flat4 >> 4;
    int jj = (flat4 & 15) * 4;
    bf16x4 o;
    #pragma unroll
    for (int q = 0; q < 4; ++q) o[q] = (__bf16)(tile[jj + q][fr] * sinv[jj + q]);
    *(bf16x4*)(hstb + (size_t)(f0 + fr) * 4096 + j0 + jj) = o;
  }
}

// ---------------- K5: h' = att @ h via bf16 MFMA + ELU ----------------
// grid (2 f-tiles, 64 i-tiles, 4 b), block 256 = 4 waves in 2x2.
__global__ __launch_bounds__(256) void k5_attn_gemm(
    const __bf16* __restrict__ hst, const float* __restrict__ f1p, const float* __restrict__ f2p,
    const ull* __restrict__ maskw, float* __restrict__ out)
{
  const int ft = blockIdx.x, it = blockIdx.y, b = blockIdx.z;
  const int tid = threadIdx.x;
  const int wid = tid >> 6, lane = tid & 63;
  const int wr = wid >> 1, wc = wid & 1;
  const int l15 = lane & 15, h4 = lane >> 4;
  const int i_w = it * 64 + wr * 32;
  const int f_blk = ft * 128;

  __shared__ __align__(16) char smemB[16384];   // [128 f][64 j] bf16, XOR-swizzled
  __shared__ float f2all[4096];

  #pragma unroll
  for (int e = 0; e < 16; ++e) {
    int idx = e * 256 + tid;
    f2all[idx] = f2p[b * 4096 + idx];
  }
  float f1r[2];
  #pragma unroll
  for (int mf = 0; mf < 2; ++mf) f1r[mf] = f1p[b * 4096 + i_w + mf * 16 + l15];

  f32x4 acc[2][4];
  #pragma unroll
  for (int mf = 0; mf < 2; ++mf)
    #pragma unroll
    for (int nf = 0; nf < 4; ++nf)
      #pragma unroll
      for (int q = 0; q < 4; ++q) acc[mf][nf][q] = 0.f;

  const char* hstB = (const char*)(hst + (size_t)b * 256 * 4096);
  __syncthreads();

  for (int g16 = 0; g16 < 16; ++g16) {
    ull w0[2], w1[2], w2[2], w3[2];
    #pragma unroll
    for (int mf = 0; mf < 2; ++mf) {
      size_t base = ((size_t)(b * 4096 + i_w + mf * 16 + l15) * 16 + g16) * 4;
      ulonglong2 p01 = *(const ulonglong2*)(maskw + base);
      ulonglong2 p23 = *(const ulonglong2*)(maskw + base + 2);
      w0[mf] = p01.x; w1[mf] = p01.y; w2[mf] = p23.x; w3[mf] = p23.y;
    }
    #pragma unroll 1
    for (int cb = 0; cb < 4; ++cb) {
      const int jc = g16 * 256 + cb * 64;
      #pragma unroll
      for (int e = 0; e < 4; ++e) {
        int c16 = e * 256 + tid;
        int f = c16 >> 3;
        int w = (c16 & 7) << 4;
        int wsz = w ^ ((f & 7) << 4);
        uint4 v = *(const uint4*)(hstB + ((size_t)(f_blk + f) * 4096 + jc) * 2 + wsz);
        *(uint4*)(smemB + f * 128 + w) = v;
      }
      __syncthreads();

      #pragma unroll
      for (int ks = 0; ks < 2; ++ks) {
        bf16x8 bfr[4];
        #pragma unroll
        for (int nf = 0; nf < 4; ++nf) {
          int f_local = wc * 64 + nf * 16 + l15;
          int byteoff = f_local * 128 + ((ks * 64 + h4 * 16) ^ ((f_local & 7) << 4));
          bfr[nf] = *(const bf16x8*)(smemB + byteoff);
        }
        const int jb = jc + ks * 32 + h4 * 8;
        float4 F0 = *(const float4*)&f2all[jb];
        float4 F1 = *(const float4*)&f2all[jb + 4];
        float f2vv[8] = {F0.x, F0.y, F0.z, F0.w, F1.x, F1.y, F1.z, F1.w};
        const int sh0 = cb * 16 + ks * 8 + h4 * 2;
        #pragma unroll
        for (int mf = 0; mf < 2; ++mf) {
          float f1v = f1r[mf];
          bf16x8 af;
          #pragma unroll
          for (int r = 0; r < 8; ++r) {
            float t = f1v + f2vv[r];
            float e = fmaxf(t, GAT_ALPHA * t);
            float p = exp2_fast(e);
            ull wsel = (r & 3) == 0 ? w0[mf] : (r & 3) == 1 ? w1[mf] : (r & 3) == 2 ? w2[mf] : w3[mf];
            af[r] = ((wsel >> (sh0 + (r >> 2))) & 1ull) ? (__bf16)p : (__bf16)0.f;
          }
          #pragma unroll
          for (int nf = 0; nf < 4; ++nf)
            acc[mf][nf] = __builtin_amdgcn_mfma_f32_16x16x32_bf16(af, bfr[nf], acc[mf][nf], 0, 0, 0);
        }
      }
      __syncthreads();
    }
  }

  float* outb = out + (size_t)b * 4096 * 256;
  #pragma unroll
  for (int mf = 0; mf < 2; ++mf)
    #pragma unroll
    for (int nf = 0; nf < 4; ++nf)
      #pragma unroll
      for (int q = 0; q < 4; ++q) {
        float x = acc[mf][nf][q];
        float o = x > 0.f ? x : __expf(x) - 1.f;   // ELU
        int i = i_w + mf * 16 + h4 * 4 + q;
        int f = f_blk + wc * 64 + nf * 16 + l15;
        outb[(size_t)i * 256 + f] = o;
      }
}

extern "C" void kernel_launch(void* const* d_in, const int* in_sizes, int n_in,
                              void* d_out, int out_size, void* d_ws, size_t ws_size,
                              hipStream_t stream) {
  const float* inp  = (const float*)d_in[0];
  const int*   adj  = (const int*)d_in[1];
  const float* W    = (const float*)d_in[2];
  const float* avec = (const float*)d_in[3];
  float* out = (float*)d_out;
  char* ws = (char*)d_ws;

  __bf16* hbf  = (__bf16*)(ws);                         // 8 MB
  __bf16* hst  = (__bf16*)(ws + 8388608);               // 8 MB
  ull*    maskw= (ull*)   (ws + 16777216);              // 8 MB
  __bf16* Wt   = (__bf16*)(ws + 25165824);              // 128 KB
  float*  f1p  = (float*) (ws + 25296896);
  float*  f2p  = (float*) (ws + 25362432);
  float*  Sfin = (float*) (ws + 25427968);
  float*  Sp   = (float*) (ws + 25493504);              // 4 MB

  k0_prep<<<dim3(4, 4), 256, 0, stream>>>(W, Wt);
  k1_mfma<<<dim3(64, 4), 256, 0, stream>>>(inp, Wt, hbf);
  k15_f12<<<4096, 256, 0, stream>>>(hbf, avec, f1p, f2p);
  k2_stream<<<dim3(8, 64, 4), 128, 0, stream>>>(adj, f1p, f2p, Sp, maskw);
  k3_combine<<<64, 256, 0, stream>>>(Sp, Sfin);
  k4_scale_T<<<dim3(64, 4, 4), 256, 0, stream>>>(hbf, Sfin, hst);
  k5_attn_gemm<<<dim3(2, 64, 4), 256, 0, stream>>>(hst, f1p, f2p, maskw, out);
}